// Round 10
// baseline (265.748 us; speedup 1.0000x reference)
//
#include <hip/hip_runtime.h>

#define HW      16384
#define C_DIM   256
#define S_DIM   256
#define T_K     128
#define NH      8
#define DH      32
#define QKV_ST  768
#define B_DIM   2
#define SCALE_F 0.17677669529663687f
#define CAND    1536
#define EQCAP   512
#define NROWS   (S_DIM * T_K)   // 32768 dense output rows per batch
#define WPACK_BLOCKS (QKV_ST * C_DIM / 4 / 256)

typedef __attribute__((ext_vector_type(8))) short short8;
typedef __attribute__((ext_vector_type(4))) float f32x4;
typedef __attribute__((ext_vector_type(4))) unsigned uint4v;

// float -> bf16 RNE via the native __bf16 type (HW v_cvt_pk_bf16_f32).
__device__ __forceinline__ short f2bf(float f) {
    union { __bf16 h; short s; } u;
    u.h = (__bf16)f;
    return u.s;
}
__device__ __forceinline__ float bf2f(short s) {
    unsigned u = ((unsigned)(unsigned short)s) << 16;
    return __uint_as_float(u);
}

// sortable key: larger key <=> larger float (no NaNs in inputs)
__device__ __forceinline__ unsigned sortkey(float f) {
    unsigned u = __float_as_uint(f);
    return (u & 0x80000000u) ? ~u : (u | 0x80000000u);
}
__device__ __forceinline__ float keyval(unsigned k) {
    return __uint_as_float((k & 0x80000000u) ? (k ^ 0x80000000u) : ~k);
}

// ---------------------------------------------------------------------------
// Kernel 1 (fused): LN stats + apply + transpose; also hosts wpack (extra
// grid-y slice) and zeroes the inverted-index count buffer (removes one
// kernel launch + one memset launch from the stream).
__launch_bounds__(256)
__global__ void ln_fused_kernel(const float* __restrict__ x,
                                const float* __restrict__ g,
                                const float* __restrict__ beta,
                                short* __restrict__ xnT,
                                const float* __restrict__ wq,
                                const float* __restrict__ wk,
                                const float* __restrict__ wv,
                                short* __restrict__ wb,
                                int* __restrict__ cnt) {
    int tid = threadIdx.x;

    // ---- wpack slice ----
    if (blockIdx.y == B_DIM) {
        if (blockIdx.x < WPACK_BLOCKS) {
            int gid  = blockIdx.x * 256 + tid;
            int base = gid * 4;
            int o = base >> 8;
            int c = base & 255;
            const float* src = (o < 256) ? wq + (size_t)o * 256
                             : (o < 512) ? wk + (size_t)(o - 256) * 256
                                         : wv + (size_t)(o - 512) * 256;
            float4 w4 = *(const float4*)(src + c);
            short4 s4;
            s4.x = f2bf(w4.x); s4.y = f2bf(w4.y); s4.z = f2bf(w4.z); s4.w = f2bf(w4.w);
            *(short4*)&wb[base] = s4;
        }
        return;
    }

    int b  = blockIdx.y;
    int n0 = blockIdx.x * 64;

    // zero this block's slice of the count buffer (used much later by topk)
    if (tid < 64) cnt[b * HW + n0 + tid] = 0;

    __shared__ float t[256][67];
    __shared__ float ps[4][64], pss[4][64];
    __shared__ float mu_s[64], rs_s[64];

    {
        int cl = tid >> 2;            // 0..63
        int ni = (tid & 3) * 16;      // pixel quarter
#pragma unroll
        for (int gset = 0; gset < 4; gset++) {
            int c = cl + gset * 64;
            const float* src = x + ((size_t)b * C_DIM + c) * HW + n0 + ni;
#pragma unroll
            for (int j = 0; j < 4; j++) {
                float4 v = *(const float4*)(src + j * 4);
                t[c][ni + j * 4 + 0] = v.x;
                t[c][ni + j * 4 + 1] = v.y;
                t[c][ni + j * 4 + 2] = v.z;
                t[c][ni + j * 4 + 3] = v.w;
            }
        }
    }
    __syncthreads();

    {
        int q = tid >> 6;
        int l = tid & 63;
        float s = 0.f, ss = 0.f;
#pragma unroll
        for (int c = 0; c < 64; c++) {
            float v = t[q * 64 + c][l];
            s += v; ss += v * v;
        }
        ps[q][l] = s; pss[q][l] = ss;
    }
    __syncthreads();
    if (tid < 64) {
        float S  = ps[0][tid] + ps[1][tid] + ps[2][tid] + ps[3][tid];
        float SS = pss[0][tid] + pss[1][tid] + pss[2][tid] + pss[3][tid];
        float m   = S * (1.f / C_DIM);
        float var = fmaxf(SS * (1.f / C_DIM) - m * m, 0.f);
        mu_s[tid] = m;
        rs_s[tid] = rsqrtf(var + 1e-5f);
    }
    __syncthreads();

    {
        int nl  = tid >> 2;           // pixel 0..63
        int ci0 = (tid & 3) * 16;     // channel quarter base
        float m  = mu_s[nl];
        float rs = rs_s[nl];
        short* dst = xnT + ((size_t)b * HW + n0 + nl) * C_DIM;
#pragma unroll
        for (int gset = 0; gset < 4; gset++) {
            int ci = ci0 + gset * 64;
            short8 s0, s1;
#pragma unroll
            for (int j = 0; j < 8; j++) {
                int c = ci + j;
                s0[j] = f2bf((t[c][nl] - m) * rs * g[c] + beta[c]);
            }
#pragma unroll
            for (int j = 0; j < 8; j++) {
                int c = ci + 8 + j;
                s1[j] = f2bf((t[c][nl] - m) * rs * g[c] + beta[c]);
            }
            *(short8*)(dst + ci)     = s0;
            *(short8*)(dst + ci + 8) = s1;
        }
    }
}

// ---------------------------------------------------------------------------
// Kernel 2: bf16 MFMA QKV projection.
// Single-buffer reg-staged pipeline (write-late, T14). LDS 18.4 KB
// -> 8 blocks/CU cap; entire 1536-block grid co-resident.
#define E_STRIDE 136
#define A_STR   36            // shorts per staged row (32 + 4 pad)
__launch_bounds__(256)
__global__ void qkv_mfma_kernel(const short* __restrict__ xnT,
                                const short* __restrict__ wb,
                                short* __restrict__ qkv) {
    int b  = blockIdx.z;
    int n0 = blockIdx.x * 128;
    int o0 = blockIdx.y * 128;
    int tid  = threadIdx.x;
    int wv   = tid >> 6;
    int wn   = wv & 1;
    int wo   = wv >> 1;
    int lane = tid & 63;
    int quad = lane >> 4;
    int ln   = lane & 15;

    __shared__ __align__(16) union {
        short S[2][128 * A_STR];      // [0=A,1=B][row*A_STR + q*8]
        short Es[64 * E_STRIDE];
    } L;

    int r1 = tid >> 2,        q1 = tid & 3;
    int r2 = (tid + 256) >> 2, q2 = (tid + 256) & 3;
    const short* gA1 = xnT + ((size_t)b * HW + n0 + r1) * C_DIM + q1 * 8;
    const short* gA2 = xnT + ((size_t)b * HW + n0 + r2) * C_DIM + q2 * 8;
    const short* gB1 = wb + (size_t)(o0 + r1) * C_DIM + q1 * 8;
    const short* gB2 = wb + (size_t)(o0 + r2) * C_DIM + q2 * 8;
    int la1 = r1 * A_STR + q1 * 8;
    int la2 = r2 * A_STR + q2 * 8;

    int aoff[4], boff[4];
#pragma unroll
    for (int mt = 0; mt < 4; mt++)
        aoff[mt] = (wn * 64 + mt * 16 + ln) * A_STR + quad * 8;
#pragma unroll
    for (int nt = 0; nt < 4; nt++)
        boff[nt] = (wo * 64 + nt * 16 + ln) * A_STR + quad * 8;

    f32x4 acc[4][4];
    const f32x4 zero4 = {0.f, 0.f, 0.f, 0.f};
#pragma unroll
    for (int mt = 0; mt < 4; mt++)
#pragma unroll
        for (int nt = 0; nt < 4; nt++) acc[mt][nt] = zero4;

    // prologue: stage step 0
    {
        short8 ra1 = *(const short8*)gA1;
        short8 ra2 = *(const short8*)gA2;
        short8 rb1 = *(const short8*)gB1;
        short8 rb2 = *(const short8*)gB2;
        *(short8*)&L.S[0][la1] = ra1;
        *(short8*)&L.S[0][la2] = ra2;
        *(short8*)&L.S[1][la1] = rb1;
        *(short8*)&L.S[1][la2] = rb2;
    }
    __syncthreads();

    for (int t = 0; t < 8; t++) {
        short8 ra1, ra2, rb1, rb2;
        if (t < 7) {
            int c0 = (t + 1) * 32;
            ra1 = *(const short8*)(gA1 + c0);
            ra2 = *(const short8*)(gA2 + c0);
            rb1 = *(const short8*)(gB1 + c0);
            rb2 = *(const short8*)(gB2 + c0);
        }

        short8 af[4], bf[4];
#pragma unroll
        for (int mt = 0; mt < 4; mt++) af[mt] = *(const short8*)&L.S[0][aoff[mt]];
#pragma unroll
        for (int nt = 0; nt < 4; nt++) bf[nt] = *(const short8*)&L.S[1][boff[nt]];
        __builtin_amdgcn_s_setprio(1);
#pragma unroll
        for (int mt = 0; mt < 4; mt++)
#pragma unroll
            for (int nt = 0; nt < 4; nt++)
                acc[mt][nt] = __builtin_amdgcn_mfma_f32_16x16x32_bf16(af[mt], bf[nt], acc[mt][nt], 0, 0, 0);
        __builtin_amdgcn_s_setprio(0);

        __syncthreads();              // all waves done reading this K-step
        if (t < 7) {
            *(short8*)&L.S[0][la1] = ra1;
            *(short8*)&L.S[0][la2] = ra2;
            *(short8*)&L.S[1][la1] = rb1;
            *(short8*)&L.S[1][la2] = rb2;
            __syncthreads();          // writes visible before next reads
        }
    }

    // two-pass epilogue: pass p drains rows [p*64, p*64+64)
#pragma unroll
    for (int p = 0; p < 2; p++) {
        if (wn == p) {
#pragma unroll
            for (int mt = 0; mt < 4; mt++)
#pragma unroll
                for (int nt = 0; nt < 4; nt++)
#pragma unroll
                    for (int r = 0; r < 4; r++)
                        L.Es[(mt * 16 + quad * 4 + r) * E_STRIDE + wo * 64 + nt * 16 + ln] =
                            f2bf(acc[mt][nt][r]);
        }
        __syncthreads();
        {
            int nl = tid >> 2;            // 0..63 local row
            int qo = (tid & 3) * 32;      // 32-col quarter
            const short* srcr = &L.Es[nl * E_STRIDE + qo];
            short* dst = qkv + ((size_t)b * HW + n0 + p * 64 + nl) * QKV_ST + o0 + qo;
#pragma unroll
            for (int j = 0; j < 4; j++)
                *(short8*)(dst + j * 8) = *(const short8*)(srcr + j * 8);
        }
        __syncthreads();
    }
}

// ---------------------------------------------------------------------------
// Kernel 3: exact top-128 per (b,s) row. 1024 threads. Emits bump the
// per-pixel inverted-index count (cnt zeroed earlier by ln_fused).
__launch_bounds__(1024)
__global__ void topk_kernel(const float* __restrict__ aff,
                            float* __restrict__ sims,
                            int* __restrict__ idx,
                            int* __restrict__ cnt) {
    int s = blockIdx.x, b = blockIdx.y;
    int tid = threadIdx.x;
    const float4* rowv4 = (const float4*)(aff + ((size_t)b * S_DIM + s) * HW);
    int* cntb = cnt + b * HW;

    __shared__ union {
        unsigned rowk[HW];                 // sortkeys, dead after pass 2
        unsigned short eqix_u[EQCAP];      // reused for tie resolution
    } U;
    __shared__ unsigned hist[256];
    __shared__ unsigned sufs[256];
    __shared__ unsigned ckey[CAND];
    __shared__ unsigned short cidx[CAND];
    __shared__ int s_sel, cHi, cCand, cEq;

    if (tid == 0) { cHi = 0; cCand = 0; cEq = 0; }
    if (tid < 256) hist[tid] = 0;
    __syncthreads();

    // ---- pass 1: compute keys, cache to LDS, histogram MSB byte ----
    for (int i = tid; i < HW / 4; i += 1024) {
        float4 v = rowv4[i];
        uint4v k;
        k[0] = sortkey(v.x); k[1] = sortkey(v.y);
        k[2] = sortkey(v.z); k[3] = sortkey(v.w);
        *(uint4v*)&U.rowk[i * 4] = k;
        atomicAdd(&hist[k[0] >> 24], 1u);
        atomicAdd(&hist[k[1] >> 24], 1u);
        atomicAdd(&hist[k[2] >> 24], 1u);
        atomicAdd(&hist[k[3] >> 24], 1u);
    }
    __syncthreads();

    // ---- suffix scan ----
    if (tid < 256) sufs[tid] = hist[tid];
    __syncthreads();
#pragma unroll
    for (int off = 1; off < 256; off <<= 1) {
        unsigned v = 0;
        if (tid < 256 && tid + off < 256) v = sufs[tid + off];
        __syncthreads();
        if (tid < 256) sufs[tid] += v;
        __syncthreads();
    }

    int kneed = T_K;
    if (tid < 256) {
        unsigned above = (tid < 255) ? sufs[tid + 1] : 0u;
        if ((int)sufs[tid] >= kneed && (int)above < kneed) s_sel = tid;
    }
    __syncthreads();
    int sel = s_sel;
    unsigned prefix = (unsigned)sel << 24;
    kneed -= (int)((sel < 255) ? sufs[sel + 1] : 0u);
    __syncthreads();

    float* so = sims + ((size_t)b * S_DIM + s) * T_K;
    int*   io = idx  + ((size_t)b * S_DIM + s) * T_K;

    // ---- pass 2 (from LDS): direct-emit above-bin, compact in-bin ----
    for (int i = tid; i < HW; i += 1024) {
        unsigned u  = U.rowk[i];
        unsigned hb = u >> 24;
        if (hb > (unsigned)sel) {
            int p = atomicAdd(&cHi, 1);
            so[p] = keyval(u); io[p] = i;
            atomicAdd(&cntb[i], 1);
        } else if (hb == (unsigned)sel) {
            int c = atomicAdd(&cCand, 1);
            if (c < CAND) { ckey[c] = u; cidx[c] = (unsigned short)i; }
        }
    }
    __syncthreads();
    int nc = min(cCand, CAND);

    // ---- 3 radix refinements over candidates ----
    for (int shift = 16; shift >= 0; shift -= 8) {
        if (tid < 256) hist[tid] = 0;
        __syncthreads();
        unsigned mask = 0xFFFFFFFFu << (shift + 8);
        for (int i = tid; i < nc; i += 1024) {
            unsigned u = ckey[i];
            if ((u & mask) == prefix) atomicAdd(&hist[(u >> shift) & 255], 1u);
        }
        __syncthreads();
        if (tid < 256) sufs[tid] = hist[tid];
        __syncthreads();
#pragma unroll
        for (int off = 1; off < 256; off <<= 1) {
            unsigned v = 0;
            if (tid < 256 && tid + off < 256) v = sufs[tid + off];
            __syncthreads();
            if (tid < 256) sufs[tid] += v;
            __syncthreads();
        }
        if (tid < 256) {
            unsigned above = (tid < 255) ? sufs[tid + 1] : 0u;
            if ((int)sufs[tid] >= kneed && (int)above < kneed) s_sel = tid;
        }
        __syncthreads();
        sel = s_sel;
        prefix |= (unsigned)sel << shift;
        kneed  -= (int)((sel < 255) ? sufs[sel + 1] : 0u);
        __syncthreads();
    }

    unsigned T = prefix;        // exact 128th-largest key
    int kneedF = kneed;
    __syncthreads();            // rowk dead; eqix_u overlay becomes live

    // ---- emit >T; compact ==T for deterministic tie resolution ----
    for (int i = tid; i < nc; i += 1024) {
        unsigned u = ckey[i];
        if (u > T) {
            int p = atomicAdd(&cHi, 1);
            so[p] = keyval(u); io[p] = cidx[i];
            atomicAdd(&cntb[cidx[i]], 1);
        } else if (u == T) {
            int q = atomicAdd(&cEq, 1);
            if (q < EQCAP) U.eqix_u[q] = cidx[i];
        }
    }
    __syncthreads();
    int m = min(cEq, EQCAP);

    // keep the kneedF SMALLEST indices among equals (jax tie order)
    float tval = keyval(T);
    for (int i = tid; i < m; i += 1024) {
        int my = U.eqix_u[i];
        int rank = 0;
        for (int j = 0; j < m; j++) rank += (U.eqix_u[j] < my);
        if (rank < kneedF) {
            so[127 - rank] = tval; io[127 - rank] = my;
            atomicAdd(&cntb[my], 1);
        }
    }
}

// ---------------------------------------------------------------------------
// Kernel 3b (fused scan+fill): one block per batch. Prefix-scan counts into
// offs; LDS fcnt initialized to offs so fill's atomic directly yields the
// slot index. Removes the fill launch + fcnt buffer + its memset.
__launch_bounds__(1024)
__global__ void scan_fill_kernel(const int* __restrict__ cnt,
                                 const int* __restrict__ idx,
                                 int* __restrict__ offs,
                                 int* __restrict__ slots) {
    int b = blockIdx.x;
    const int* c = cnt + b * HW;
    int* o = offs + b * HW;
    int tid = threadIdx.x;

    __shared__ int part[1024];
    __shared__ int fcntL[HW];       // 64 KB

    int base = tid * 16;
    int loc[16];
    int s = 0;
#pragma unroll
    for (int j = 0; j < 16; j++) { loc[j] = s; s += c[base + j]; }
    part[tid] = s;
    __syncthreads();
    for (int off = 1; off < 1024; off <<= 1) {
        int v = (tid >= off) ? part[tid - off] : 0;
        __syncthreads();
        part[tid] += v;
        __syncthreads();
    }
    int pre = (tid == 0) ? 0 : part[tid - 1];
#pragma unroll
    for (int j = 0; j < 16; j++) {
        int ov = pre + loc[j];
        o[base + j]     = ov;       // global copy for transpose_add
        fcntL[base + j] = ov;       // LDS running cursor for fill
    }
    __syncthreads();

    // fill phase: slots[cursor(n)++] = dense row id
    const int* ib = idx + (size_t)b * NROWS;
    int* sb = slots + (size_t)b * NROWS;
    for (int i = tid; i < NROWS; i += 1024) {
        int n = ib[i];
        int slot = atomicAdd(&fcntL[n], 1);
        sb[slot] = i;
    }
}

// ---------------------------------------------------------------------------
// Kernel 4: MFMA attention per (b, s, h). No-max softmax (scores bounded);
// sims folded into V at staging.
#define K_STRIDE 40
#define VT_STRIDE 132
union KPu {
    short K[T_K * K_STRIDE];
    short P[4][16 * VT_STRIDE];
};
__launch_bounds__(256)
__global__ void attn_kernel(const short* __restrict__ qkv,
                            const float* __restrict__ sims,
                            const int* __restrict__ idx,
                            float* __restrict__ dout) {
    int s = blockIdx.x, h = blockIdx.y, b = blockIdx.z;
    int tid  = threadIdx.x;
    int wv   = tid >> 6;
    int lane = tid & 63;
    int quad = lane >> 4;
    int ln   = lane & 15;

    __shared__ __align__(16) KPu KP;
    __shared__ __align__(16) short Vt[DH * VT_STRIDE];
    __shared__ float sim_s[T_K];
    __shared__ int   idx_s[T_K];

    if (tid < T_K) {
        sim_s[tid] = sims[((size_t)b * S_DIM + s) * T_K + tid];
        idx_s[tid] = idx [((size_t)b * S_DIM + s) * T_K + tid];
    }
    __syncthreads();

    const short* qkvb = qkv + (size_t)b * HW * QKV_ST;
    int co = h * DH;

    {
        int r  = tid >> 1;
        int hh = tid & 1;
        const short* base = qkvb + (size_t)idx_s[r] * QKV_ST + co + hh * 16;
        short8 k0 = *(const short8*)(base + 256);
        short8 k1 = *(const short8*)(base + 256 + 8);
        *(short8*)&KP.K[r * K_STRIDE + hh * 16]     = k0;
        *(short8*)&KP.K[r * K_STRIDE + hh * 16 + 8] = k1;
        float suR = sim_s[r];
        short8 v0 = *(const short8*)(base + 512);
        short8 v1 = *(const short8*)(base + 512 + 8);
#pragma unroll
        for (int i = 0; i < 8; i++)
            Vt[(hh * 16 + i) * VT_STRIDE + r]     = f2bf(bf2f(v0[i]) * suR);
#pragma unroll
        for (int i = 0; i < 8; i++)
            Vt[(hh * 16 + 8 + i) * VT_STRIDE + r] = f2bf(bf2f(v1[i]) * suR);
    }

    short8 aq[2];
#pragma unroll
    for (int mt = 0; mt < 2; mt++) {
        int t = wv * 32 + mt * 16 + ln;
        aq[mt] = *(const short8*)(qkvb + (size_t)idx_s[t] * QKV_ST + co + quad * 8);
    }
    __syncthreads();

    f32x4 S[2][8];
    const f32x4 zero4 = {0.f, 0.f, 0.f, 0.f};
    __builtin_amdgcn_s_setprio(1);
#pragma unroll
    for (int nt = 0; nt < 8; nt++) {
        short8 kf = *(const short8*)&KP.K[(nt * 16 + ln) * K_STRIDE + quad * 8];
        S[0][nt] = __builtin_amdgcn_mfma_f32_16x16x32_bf16(aq[0], kf, zero4, 0, 0, 0);
        S[1][nt] = __builtin_amdgcn_mfma_f32_16x16x32_bf16(aq[1], kf, zero4, 0, 0, 0);
    }
    __builtin_amdgcn_s_setprio(0);

    // no-max softmax: exp(s*scale) directly, row-sum only
    float lrow[2][4];
#pragma unroll
    for (int mt = 0; mt < 2; mt++) {
#pragma unroll
        for (int r = 0; r < 4; r++) {
            float l = 0.f;
#pragma unroll
            for (int nt = 0; nt < 8; nt++) {
                float p = __expf(S[mt][nt][r] * SCALE_F);
                S[mt][nt][r] = p;
                l += p;
            }
            l += __shfl_xor(l, 1, 64);
            l += __shfl_xor(l, 2, 64);
            l += __shfl_xor(l, 4, 64);
            l += __shfl_xor(l, 8, 64);
            lrow[mt][r] = l;
        }
    }

    // One barrier: all waves done reading KP.K before any wave writes KP.P.
    __syncthreads();

    float* db = dout + ((size_t)b * NROWS + s * T_K) * C_DIM + co;
#pragma unroll
    for (int mt = 0; mt < 2; mt++) {
        float w[4];
#pragma unroll
        for (int r = 0; r < 4; r++)
            w[r] = sim_s[wv * 32 + mt * 16 + quad * 4 + r] / lrow[mt][r];

#pragma unroll
        for (int nt = 0; nt < 8; nt++) {
#pragma unroll
            for (int r = 0; r < 4; r++)
                KP.P[wv][(quad * 4 + r) * VT_STRIDE + nt * 16 + ln] = f2bf(S[mt][nt][r]);
        }

        f32x4 O[2] = {zero4, zero4};
        __builtin_amdgcn_s_setprio(1);
#pragma unroll
        for (int kt = 0; kt < 4; kt++) {
            short8 pa = *(const short8*)&KP.P[wv][ln * VT_STRIDE + kt * 32 + quad * 8];
#pragma unroll
            for (int nt2 = 0; nt2 < 2; nt2++) {
                short8 vb = *(const short8*)&Vt[(nt2 * 16 + ln) * VT_STRIDE + kt * 32 + quad * 8];
                O[nt2] = __builtin_amdgcn_mfma_f32_16x16x32_bf16(pa, vb, O[nt2], 0, 0, 0);
            }
        }
        __builtin_amdgcn_s_setprio(0);

#pragma unroll
        for (int nt2 = 0; nt2 < 2; nt2++)
#pragma unroll
            for (int r = 0; r < 4; r++) {
                int t = wv * 32 + mt * 16 + quad * 4 + r;
                db[(size_t)t * C_DIM + nt2 * 16 + ln] = O[nt2][r] * w[r];
            }
    }
}

// ---------------------------------------------------------------------------
// Kernel 5: gather + transpose: out[b][c][n] = v[b][n][c] + sum of dout rows.
__launch_bounds__(256)
__global__ void transpose_add_kernel(const short* __restrict__ qkv,
                                     const float* __restrict__ dout,
                                     const int* __restrict__ cnt,
                                     const int* __restrict__ offs,
                                     const int* __restrict__ slots,
                                     float* __restrict__ out) {
    int b  = blockIdx.z;
    int n0 = blockIdx.x * 32;
    int c0 = blockIdx.y * 128;
    int x4 = threadIdx.x & 31;        // float4 index within 128-ch half
    int y  = threadIdx.x >> 5;        // 0..7 pixel group

    const float* doutb = dout + (size_t)b * NROWS * C_DIM;
    const int*   slb   = slots + (size_t)b * NROWS;

    __shared__ float t[32][129];

#pragma unroll
    for (int r = 0; r < 4; r++) {
        int px = y + 8 * r;
        int n  = n0 + px;
        size_t row = (size_t)b * HW + n;
        short4 vs = *(const short4*)(qkv + row * QKV_ST + 512 + c0 + x4 * 4);
        float a0 = bf2f(vs.x), a1 = bf2f(vs.y), a2 = bf2f(vs.z), a3 = bf2f(vs.w);
        int cn = cnt[b * HW + n];
        int of = offs[b * HW + n];
        for (int j = 0; j < cn; j++) {
            int dr = slb[of + j];
            float4 d = *(const float4*)(doutb + (size_t)dr * C_DIM + c0 + x4 * 4);
            a0 += d.x; a1 += d.y; a2 += d.z; a3 += d.w;
        }
        t[px][x4 * 4 + 0] = a0;
        t[px][x4 * 4 + 1] = a1;
        t[px][x4 * 4 + 2] = a2;
        t[px][x4 * 4 + 3] = a3;
    }
    __syncthreads();

    {
        int nl = threadIdx.x & 31;            // pixel lane
        int cg = threadIdx.x >> 5;            // 0..7 channel group (16 each)
#pragma unroll
        for (int cc = 0; cc < 16; cc++) {
            int c = c0 + cg * 16 + cc;
            out[((size_t)b * C_DIM + c) * HW + n0 + nl] = t[nl][cg * 16 + cc];
        }
    }
}

// ---------------------------------------------------------------------------
extern "C" void kernel_launch(void* const* d_in, const int* in_sizes, int n_in,
                              void* d_out, int out_size, void* d_ws, size_t ws_size,
                              hipStream_t stream) {
    const float* x    = (const float*)d_in[0];
    const float* aff  = (const float*)d_in[1];
    const float* g    = (const float*)d_in[2];
    const float* beta = (const float*)d_in[3];
    const float* wq   = (const float*)d_in[4];
    const float* wk   = (const float*)d_in[5];
    const float* wv   = (const float*)d_in[6];
    float* out = (float*)d_out;

    char* ws = (char*)d_ws;
    short* qkv  = (short*)ws;                                   ws += (size_t)B_DIM * HW * QKV_ST * 2;
    short* xnT  = (short*)ws;                                   ws += (size_t)B_DIM * HW * C_DIM * 2;
    short* wbuf = (short*)ws;                                   ws += (size_t)QKV_ST * C_DIM * 2;
    float* simsb= (float*)ws;                                   ws += (size_t)B_DIM * S_DIM * T_K * 4;
    int*   idxb = (int*)ws;                                     ws += (size_t)B_DIM * S_DIM * T_K * 4;
    int*   cntb = (int*)ws;                                     ws += (size_t)B_DIM * HW * 4;
    int*   offsb= (int*)ws;                                     ws += (size_t)B_DIM * HW * 4;
    int*   slots= (int*)ws;                                     ws += (size_t)B_DIM * NROWS * 4;
    float* dout = (float*)ws;

    ln_fused_kernel<<<dim3(HW / 64, B_DIM + 1), 256, 0, stream>>>(
        x, g, beta, xnT, wq, wk, wv, wbuf, cntb);
    qkv_mfma_kernel<<<dim3(HW / 128, QKV_ST / 128, B_DIM), 256, 0, stream>>>(
        xnT, wbuf, qkv);
    topk_kernel<<<dim3(S_DIM, B_DIM), 1024, 0, stream>>>(aff, simsb, idxb, cntb);
    scan_fill_kernel<<<dim3(B_DIM), 1024, 0, stream>>>(cntb, idxb, offsb, slots);
    attn_kernel<<<dim3(S_DIM, NH, B_DIM), 256, 0, stream>>>(qkv, simsb, idxb, dout);
    transpose_add_kernel<<<dim3(HW / 32, C_DIM / 128, B_DIM), 256, 0, stream>>>(
        qkv, dout, cntb, offsb, slots, out);
}

// Round 11
// 241.207 us; speedup vs baseline: 1.1017x; 1.1017x over previous
//
#include <hip/hip_runtime.h>

#define HW      16384
#define C_DIM   256
#define S_DIM   256
#define T_K     128
#define NH      8
#define DH      32
#define QKV_ST  768
#define B_DIM   2
#define SCALE_F 0.17677669529663687f
#define CAND    1536
#define EQCAP   512
#define NROWS   (S_DIM * T_K)   // 32768 dense output rows per batch
#define WPACK_BLOCKS (QKV_ST * C_DIM / 4 / 256)

typedef __attribute__((ext_vector_type(8))) short short8;
typedef __attribute__((ext_vector_type(4))) float f32x4;
typedef __attribute__((ext_vector_type(4))) unsigned uint4v;

// float -> bf16 RNE via the native __bf16 type (HW v_cvt_pk_bf16_f32).
__device__ __forceinline__ short f2bf(float f) {
    union { __bf16 h; short s; } u;
    u.h = (__bf16)f;
    return u.s;
}
__device__ __forceinline__ float bf2f(short s) {
    unsigned u = ((unsigned)(unsigned short)s) << 16;
    return __uint_as_float(u);
}

// sortable key: larger key <=> larger float (no NaNs in inputs)
__device__ __forceinline__ unsigned sortkey(float f) {
    unsigned u = __float_as_uint(f);
    return (u & 0x80000000u) ? ~u : (u | 0x80000000u);
}
__device__ __forceinline__ float keyval(unsigned k) {
    return __uint_as_float((k & 0x80000000u) ? (k ^ 0x80000000u) : ~k);
}

// ---------------------------------------------------------------------------
// Kernel 1 (fused): LN stats + apply + transpose; hosts wpack (extra grid-y
// slice) and zeroes cnt + fcnt (replaces both memset launches).
__launch_bounds__(256)
__global__ void ln_fused_kernel(const float* __restrict__ x,
                                const float* __restrict__ g,
                                const float* __restrict__ beta,
                                short* __restrict__ xnT,
                                const float* __restrict__ wq,
                                const float* __restrict__ wk,
                                const float* __restrict__ wv,
                                short* __restrict__ wb,
                                int* __restrict__ cnt,
                                int* __restrict__ fcnt) {
    int tid = threadIdx.x;

    // ---- wpack slice ----
    if (blockIdx.y == B_DIM) {
        if (blockIdx.x < WPACK_BLOCKS) {
            int gid  = blockIdx.x * 256 + tid;
            int base = gid * 4;
            int o = base >> 8;
            int c = base & 255;
            const float* src = (o < 256) ? wq + (size_t)o * 256
                             : (o < 512) ? wk + (size_t)(o - 256) * 256
                                         : wv + (size_t)(o - 512) * 256;
            float4 w4 = *(const float4*)(src + c);
            short4 s4;
            s4.x = f2bf(w4.x); s4.y = f2bf(w4.y); s4.z = f2bf(w4.z); s4.w = f2bf(w4.w);
            *(short4*)&wb[base] = s4;
        }
        return;
    }

    int b  = blockIdx.y;
    int n0 = blockIdx.x * 64;

    // zero this block's slice of the index-count buffers
    if (tid < 64) {
        cnt [b * HW + n0 + tid] = 0;
        fcnt[b * HW + n0 + tid] = 0;
    }

    __shared__ float t[256][67];
    __shared__ float ps[4][64], pss[4][64];
    __shared__ float mu_s[64], rs_s[64];

    {
        int cl = tid >> 2;            // 0..63
        int ni = (tid & 3) * 16;      // pixel quarter
#pragma unroll
        for (int gset = 0; gset < 4; gset++) {
            int c = cl + gset * 64;
            const float* src = x + ((size_t)b * C_DIM + c) * HW + n0 + ni;
#pragma unroll
            for (int j = 0; j < 4; j++) {
                float4 v = *(const float4*)(src + j * 4);
                t[c][ni + j * 4 + 0] = v.x;
                t[c][ni + j * 4 + 1] = v.y;
                t[c][ni + j * 4 + 2] = v.z;
                t[c][ni + j * 4 + 3] = v.w;
            }
        }
    }
    __syncthreads();

    {
        int q = tid >> 6;
        int l = tid & 63;
        float s = 0.f, ss = 0.f;
#pragma unroll
        for (int c = 0; c < 64; c++) {
            float v = t[q * 64 + c][l];
            s += v; ss += v * v;
        }
        ps[q][l] = s; pss[q][l] = ss;
    }
    __syncthreads();
    if (tid < 64) {
        float S  = ps[0][tid] + ps[1][tid] + ps[2][tid] + ps[3][tid];
        float SS = pss[0][tid] + pss[1][tid] + pss[2][tid] + pss[3][tid];
        float m   = S * (1.f / C_DIM);
        float var = fmaxf(SS * (1.f / C_DIM) - m * m, 0.f);
        mu_s[tid] = m;
        rs_s[tid] = rsqrtf(var + 1e-5f);
    }
    __syncthreads();

    {
        int nl  = tid >> 2;           // pixel 0..63
        int ci0 = (tid & 3) * 16;     // channel quarter base
        float m  = mu_s[nl];
        float rs = rs_s[nl];
        short* dst = xnT + ((size_t)b * HW + n0 + nl) * C_DIM;
#pragma unroll
        for (int gset = 0; gset < 4; gset++) {
            int ci = ci0 + gset * 64;
            short8 s0, s1;
#pragma unroll
            for (int j = 0; j < 8; j++) {
                int c = ci + j;
                s0[j] = f2bf((t[c][nl] - m) * rs * g[c] + beta[c]);
            }
#pragma unroll
            for (int j = 0; j < 8; j++) {
                int c = ci + 8 + j;
                s1[j] = f2bf((t[c][nl] - m) * rs * g[c] + beta[c]);
            }
            *(short8*)(dst + ci)     = s0;
            *(short8*)(dst + ci + 8) = s1;
        }
    }
}

// ---------------------------------------------------------------------------
// Kernel 2: bf16 MFMA QKV projection.
// Single-buffer reg-staged pipeline (write-late, T14). LDS 18.4 KB
// -> 8 blocks/CU cap; entire 1536-block grid co-resident.
#define E_STRIDE 136
#define A_STR   36            // shorts per staged row (32 + 4 pad)
__launch_bounds__(256)
__global__ void qkv_mfma_kernel(const short* __restrict__ xnT,
                                const short* __restrict__ wb,
                                short* __restrict__ qkv) {
    int b  = blockIdx.z;
    int n0 = blockIdx.x * 128;
    int o0 = blockIdx.y * 128;
    int tid  = threadIdx.x;
    int wv   = tid >> 6;
    int wn   = wv & 1;
    int wo   = wv >> 1;
    int lane = tid & 63;
    int quad = lane >> 4;
    int ln   = lane & 15;

    __shared__ __align__(16) union {
        short S[2][128 * A_STR];      // [0=A,1=B][row*A_STR + q*8]
        short Es[64 * E_STRIDE];
    } L;

    int r1 = tid >> 2,        q1 = tid & 3;
    int r2 = (tid + 256) >> 2, q2 = (tid + 256) & 3;
    const short* gA1 = xnT + ((size_t)b * HW + n0 + r1) * C_DIM + q1 * 8;
    const short* gA2 = xnT + ((size_t)b * HW + n0 + r2) * C_DIM + q2 * 8;
    const short* gB1 = wb + (size_t)(o0 + r1) * C_DIM + q1 * 8;
    const short* gB2 = wb + (size_t)(o0 + r2) * C_DIM + q2 * 8;
    int la1 = r1 * A_STR + q1 * 8;
    int la2 = r2 * A_STR + q2 * 8;

    int aoff[4], boff[4];
#pragma unroll
    for (int mt = 0; mt < 4; mt++)
        aoff[mt] = (wn * 64 + mt * 16 + ln) * A_STR + quad * 8;
#pragma unroll
    for (int nt = 0; nt < 4; nt++)
        boff[nt] = (wo * 64 + nt * 16 + ln) * A_STR + quad * 8;

    f32x4 acc[4][4];
    const f32x4 zero4 = {0.f, 0.f, 0.f, 0.f};
#pragma unroll
    for (int mt = 0; mt < 4; mt++)
#pragma unroll
        for (int nt = 0; nt < 4; nt++) acc[mt][nt] = zero4;

    // prologue: stage step 0
    {
        short8 ra1 = *(const short8*)gA1;
        short8 ra2 = *(const short8*)gA2;
        short8 rb1 = *(const short8*)gB1;
        short8 rb2 = *(const short8*)gB2;
        *(short8*)&L.S[0][la1] = ra1;
        *(short8*)&L.S[0][la2] = ra2;
        *(short8*)&L.S[1][la1] = rb1;
        *(short8*)&L.S[1][la2] = rb2;
    }
    __syncthreads();

    for (int t = 0; t < 8; t++) {
        short8 ra1, ra2, rb1, rb2;
        if (t < 7) {
            int c0 = (t + 1) * 32;
            ra1 = *(const short8*)(gA1 + c0);
            ra2 = *(const short8*)(gA2 + c0);
            rb1 = *(const short8*)(gB1 + c0);
            rb2 = *(const short8*)(gB2 + c0);
        }

        short8 af[4], bf[4];
#pragma unroll
        for (int mt = 0; mt < 4; mt++) af[mt] = *(const short8*)&L.S[0][aoff[mt]];
#pragma unroll
        for (int nt = 0; nt < 4; nt++) bf[nt] = *(const short8*)&L.S[1][boff[nt]];
        __builtin_amdgcn_s_setprio(1);
#pragma unroll
        for (int mt = 0; mt < 4; mt++)
#pragma unroll
            for (int nt = 0; nt < 4; nt++)
                acc[mt][nt] = __builtin_amdgcn_mfma_f32_16x16x32_bf16(af[mt], bf[nt], acc[mt][nt], 0, 0, 0);
        __builtin_amdgcn_s_setprio(0);

        __syncthreads();              // all waves done reading this K-step
        if (t < 7) {
            *(short8*)&L.S[0][la1] = ra1;
            *(short8*)&L.S[0][la2] = ra2;
            *(short8*)&L.S[1][la1] = rb1;
            *(short8*)&L.S[1][la2] = rb2;
            __syncthreads();          // writes visible before next reads
        }
    }

    // two-pass epilogue: pass p drains rows [p*64, p*64+64)
#pragma unroll
    for (int p = 0; p < 2; p++) {
        if (wn == p) {
#pragma unroll
            for (int mt = 0; mt < 4; mt++)
#pragma unroll
                for (int nt = 0; nt < 4; nt++)
#pragma unroll
                    for (int r = 0; r < 4; r++)
                        L.Es[(mt * 16 + quad * 4 + r) * E_STRIDE + wo * 64 + nt * 16 + ln] =
                            f2bf(acc[mt][nt][r]);
        }
        __syncthreads();
        {
            int nl = tid >> 2;            // 0..63 local row
            int qo = (tid & 3) * 32;      // 32-col quarter
            const short* srcr = &L.Es[nl * E_STRIDE + qo];
            short* dst = qkv + ((size_t)b * HW + n0 + p * 64 + nl) * QKV_ST + o0 + qo;
#pragma unroll
            for (int j = 0; j < 4; j++)
                *(short8*)(dst + j * 8) = *(const short8*)(srcr + j * 8);
        }
        __syncthreads();
    }
}

// ---------------------------------------------------------------------------
// Kernel 3: exact top-128 per (b,s) row. 1024 threads. Emits bump the
// per-pixel inverted-index count (cnt zeroed earlier by ln_fused).
__launch_bounds__(1024)
__global__ void topk_kernel(const float* __restrict__ aff,
                            float* __restrict__ sims,
                            int* __restrict__ idx,
                            int* __restrict__ cnt) {
    int s = blockIdx.x, b = blockIdx.y;
    int tid = threadIdx.x;
    const float4* rowv4 = (const float4*)(aff + ((size_t)b * S_DIM + s) * HW);
    int* cntb = cnt + b * HW;

    __shared__ union {
        unsigned rowk[HW];                 // sortkeys, dead after pass 2
        unsigned short eqix_u[EQCAP];      // reused for tie resolution
    } U;
    __shared__ unsigned hist[256];
    __shared__ unsigned sufs[256];
    __shared__ unsigned ckey[CAND];
    __shared__ unsigned short cidx[CAND];
    __shared__ int s_sel, cHi, cCand, cEq;

    if (tid == 0) { cHi = 0; cCand = 0; cEq = 0; }
    if (tid < 256) hist[tid] = 0;
    __syncthreads();

    // ---- pass 1: compute keys, cache to LDS, histogram MSB byte ----
    for (int i = tid; i < HW / 4; i += 1024) {
        float4 v = rowv4[i];
        uint4v k;
        k[0] = sortkey(v.x); k[1] = sortkey(v.y);
        k[2] = sortkey(v.z); k[3] = sortkey(v.w);
        *(uint4v*)&U.rowk[i * 4] = k;
        atomicAdd(&hist[k[0] >> 24], 1u);
        atomicAdd(&hist[k[1] >> 24], 1u);
        atomicAdd(&hist[k[2] >> 24], 1u);
        atomicAdd(&hist[k[3] >> 24], 1u);
    }
    __syncthreads();

    // ---- suffix scan ----
    if (tid < 256) sufs[tid] = hist[tid];
    __syncthreads();
#pragma unroll
    for (int off = 1; off < 256; off <<= 1) {
        unsigned v = 0;
        if (tid < 256 && tid + off < 256) v = sufs[tid + off];
        __syncthreads();
        if (tid < 256) sufs[tid] += v;
        __syncthreads();
    }

    int kneed = T_K;
    if (tid < 256) {
        unsigned above = (tid < 255) ? sufs[tid + 1] : 0u;
        if ((int)sufs[tid] >= kneed && (int)above < kneed) s_sel = tid;
    }
    __syncthreads();
    int sel = s_sel;
    unsigned prefix = (unsigned)sel << 24;
    kneed -= (int)((sel < 255) ? sufs[sel + 1] : 0u);
    __syncthreads();

    float* so = sims + ((size_t)b * S_DIM + s) * T_K;
    int*   io = idx  + ((size_t)b * S_DIM + s) * T_K;

    // ---- pass 2 (from LDS): direct-emit above-bin, compact in-bin ----
    for (int i = tid; i < HW; i += 1024) {
        unsigned u  = U.rowk[i];
        unsigned hb = u >> 24;
        if (hb > (unsigned)sel) {
            int p = atomicAdd(&cHi, 1);
            so[p] = keyval(u); io[p] = i;
            atomicAdd(&cntb[i], 1);
        } else if (hb == (unsigned)sel) {
            int c = atomicAdd(&cCand, 1);
            if (c < CAND) { ckey[c] = u; cidx[c] = (unsigned short)i; }
        }
    }
    __syncthreads();
    int nc = min(cCand, CAND);

    // ---- 3 radix refinements over candidates ----
    for (int shift = 16; shift >= 0; shift -= 8) {
        if (tid < 256) hist[tid] = 0;
        __syncthreads();
        unsigned mask = 0xFFFFFFFFu << (shift + 8);
        for (int i = tid; i < nc; i += 1024) {
            unsigned u = ckey[i];
            if ((u & mask) == prefix) atomicAdd(&hist[(u >> shift) & 255], 1u);
        }
        __syncthreads();
        if (tid < 256) sufs[tid] = hist[tid];
        __syncthreads();
#pragma unroll
        for (int off = 1; off < 256; off <<= 1) {
            unsigned v = 0;
            if (tid < 256 && tid + off < 256) v = sufs[tid + off];
            __syncthreads();
            if (tid < 256) sufs[tid] += v;
            __syncthreads();
        }
        if (tid < 256) {
            unsigned above = (tid < 255) ? sufs[tid + 1] : 0u;
            if ((int)sufs[tid] >= kneed && (int)above < kneed) s_sel = tid;
        }
        __syncthreads();
        sel = s_sel;
        prefix |= (unsigned)sel << shift;
        kneed  -= (int)((sel < 255) ? sufs[sel + 1] : 0u);
        __syncthreads();
    }

    unsigned T = prefix;        // exact 128th-largest key
    int kneedF = kneed;
    __syncthreads();            // rowk dead; eqix_u overlay becomes live

    // ---- emit >T; compact ==T for deterministic tie resolution ----
    for (int i = tid; i < nc; i += 1024) {
        unsigned u = ckey[i];
        if (u > T) {
            int p = atomicAdd(&cHi, 1);
            so[p] = keyval(u); io[p] = cidx[i];
            atomicAdd(&cntb[cidx[i]], 1);
        } else if (u == T) {
            int q = atomicAdd(&cEq, 1);
            if (q < EQCAP) U.eqix_u[q] = cidx[i];
        }
    }
    __syncthreads();
    int m = min(cEq, EQCAP);

    // keep the kneedF SMALLEST indices among equals (jax tie order)
    float tval = keyval(T);
    for (int i = tid; i < m; i += 1024) {
        int my = U.eqix_u[i];
        int rank = 0;
        for (int j = 0; j < m; j++) rank += (U.eqix_u[j] < my);
        if (rank < kneedF) {
            so[127 - rank] = tval; io[127 - rank] = my;
            atomicAdd(&cntb[my], 1);
        }
    }
}

// ---------------------------------------------------------------------------
// Kernel 3b: prefix scan (1 block per batch) — cheap; fill stays wide.
__launch_bounds__(1024)
__global__ void scan_kernel(const int* __restrict__ cnt,
                            int* __restrict__ offs) {
    int b = blockIdx.x;
    const int* c = cnt + b * HW;
    int* o = offs + b * HW;
    int tid = threadIdx.x;
    __shared__ int part[1024];
    int base = tid * 16;
    int loc[16];
    int s = 0;
#pragma unroll
    for (int j = 0; j < 16; j++) { loc[j] = s; s += c[base + j]; }
    part[tid] = s;
    __syncthreads();
    for (int off = 1; off < 1024; off <<= 1) {
        int v = (tid >= off) ? part[tid - off] : 0;
        __syncthreads();
        part[tid] += v;
        __syncthreads();
    }
    int pre = (tid == 0) ? 0 : part[tid - 1];
#pragma unroll
    for (int j = 0; j < 16; j++) o[base + j] = pre + loc[j];
}

// Kernel 3c: wide fill (65536 threads — one dense row each).
__global__ void fill_kernel(const int* __restrict__ idx,
                            const int* __restrict__ offs,
                            int* __restrict__ fcnt,
                            int* __restrict__ slots) {
    int b = blockIdx.y;
    int i = blockIdx.x * 256 + threadIdx.x;           // dense row id
    int n = idx[(size_t)b * NROWS + i];
    int r = atomicAdd(&fcnt[b * HW + n], 1);
    slots[(size_t)b * NROWS + offs[b * HW + n] + r] = i;
}

// ---------------------------------------------------------------------------
// Kernel 4: MFMA attention per (b, s, h). No-max softmax (scores bounded);
// sims folded into V at staging.
#define K_STRIDE 40
#define VT_STRIDE 132
union KPu {
    short K[T_K * K_STRIDE];
    short P[4][16 * VT_STRIDE];
};
__launch_bounds__(256)
__global__ void attn_kernel(const short* __restrict__ qkv,
                            const float* __restrict__ sims,
                            const int* __restrict__ idx,
                            float* __restrict__ dout) {
    int s = blockIdx.x, h = blockIdx.y, b = blockIdx.z;
    int tid  = threadIdx.x;
    int wv   = tid >> 6;
    int lane = tid & 63;
    int quad = lane >> 4;
    int ln   = lane & 15;

    __shared__ __align__(16) KPu KP;
    __shared__ __align__(16) short Vt[DH * VT_STRIDE];
    __shared__ float sim_s[T_K];
    __shared__ int   idx_s[T_K];

    if (tid < T_K) {
        sim_s[tid] = sims[((size_t)b * S_DIM + s) * T_K + tid];
        idx_s[tid] = idx [((size_t)b * S_DIM + s) * T_K + tid];
    }
    __syncthreads();

    const short* qkvb = qkv + (size_t)b * HW * QKV_ST;
    int co = h * DH;

    {
        int r  = tid >> 1;
        int hh = tid & 1;
        const short* base = qkvb + (size_t)idx_s[r] * QKV_ST + co + hh * 16;
        short8 k0 = *(const short8*)(base + 256);
        short8 k1 = *(const short8*)(base + 256 + 8);
        *(short8*)&KP.K[r * K_STRIDE + hh * 16]     = k0;
        *(short8*)&KP.K[r * K_STRIDE + hh * 16 + 8] = k1;
        float suR = sim_s[r];
        short8 v0 = *(const short8*)(base + 512);
        short8 v1 = *(const short8*)(base + 512 + 8);
#pragma unroll
        for (int i = 0; i < 8; i++)
            Vt[(hh * 16 + i) * VT_STRIDE + r]     = f2bf(bf2f(v0[i]) * suR);
#pragma unroll
        for (int i = 0; i < 8; i++)
            Vt[(hh * 16 + 8 + i) * VT_STRIDE + r] = f2bf(bf2f(v1[i]) * suR);
    }

    short8 aq[2];
#pragma unroll
    for (int mt = 0; mt < 2; mt++) {
        int t = wv * 32 + mt * 16 + ln;
        aq[mt] = *(const short8*)(qkvb + (size_t)idx_s[t] * QKV_ST + co + quad * 8);
    }
    __syncthreads();

    f32x4 S[2][8];
    const f32x4 zero4 = {0.f, 0.f, 0.f, 0.f};
    __builtin_amdgcn_s_setprio(1);
#pragma unroll
    for (int nt = 0; nt < 8; nt++) {
        short8 kf = *(const short8*)&KP.K[(nt * 16 + ln) * K_STRIDE + quad * 8];
        S[0][nt] = __builtin_amdgcn_mfma_f32_16x16x32_bf16(aq[0], kf, zero4, 0, 0, 0);
        S[1][nt] = __builtin_amdgcn_mfma_f32_16x16x32_bf16(aq[1], kf, zero4, 0, 0, 0);
    }
    __builtin_amdgcn_s_setprio(0);

    // no-max softmax: exp(s*scale) directly, row-sum only
    float lrow[2][4];
#pragma unroll
    for (int mt = 0; mt < 2; mt++) {
#pragma unroll
        for (int r = 0; r < 4; r++) {
            float l = 0.f;
#pragma unroll
            for (int nt = 0; nt < 8; nt++) {
                float p = __expf(S[mt][nt][r] * SCALE_F);
                S[mt][nt][r] = p;
                l += p;
            }
            l += __shfl_xor(l, 1, 64);
            l += __shfl_xor(l, 2, 64);
            l += __shfl_xor(l, 4, 64);
            l += __shfl_xor(l, 8, 64);
            lrow[mt][r] = l;
        }
    }

    // One barrier: all waves done reading KP.K before any wave writes KP.P.
    __syncthreads();

    float* db = dout + ((size_t)b * NROWS + s * T_K) * C_DIM + co;
#pragma unroll
    for (int mt = 0; mt < 2; mt++) {
        float w[4];
#pragma unroll
        for (int r = 0; r < 4; r++)
            w[r] = sim_s[wv * 32 + mt * 16 + quad * 4 + r] / lrow[mt][r];

#pragma unroll
        for (int nt = 0; nt < 8; nt++) {
#pragma unroll
            for (int r = 0; r < 4; r++)
                KP.P[wv][(quad * 4 + r) * VT_STRIDE + nt * 16 + ln] = f2bf(S[mt][nt][r]);
        }

        f32x4 O[2] = {zero4, zero4};
        __builtin_amdgcn_s_setprio(1);
#pragma unroll
        for (int kt = 0; kt < 4; kt++) {
            short8 pa = *(const short8*)&KP.P[wv][ln * VT_STRIDE + kt * 32 + quad * 8];
#pragma unroll
            for (int nt2 = 0; nt2 < 2; nt2++) {
                short8 vb = *(const short8*)&Vt[(nt2 * 16 + ln) * VT_STRIDE + kt * 32 + quad * 8];
                O[nt2] = __builtin_amdgcn_mfma_f32_16x16x32_bf16(pa, vb, O[nt2], 0, 0, 0);
            }
        }
        __builtin_amdgcn_s_setprio(0);

#pragma unroll
        for (int nt2 = 0; nt2 < 2; nt2++)
#pragma unroll
            for (int r = 0; r < 4; r++) {
                int t = wv * 32 + mt * 16 + quad * 4 + r;
                db[(size_t)t * C_DIM + nt2 * 16 + ln] = O[nt2][r] * w[r];
            }
    }
}

// ---------------------------------------------------------------------------
// Kernel 5: gather + transpose: out[b][c][n] = v[b][n][c] + sum of dout rows.
__launch_bounds__(256)
__global__ void transpose_add_kernel(const short* __restrict__ qkv,
                                     const float* __restrict__ dout,
                                     const int* __restrict__ cnt,
                                     const int* __restrict__ offs,
                                     const int* __restrict__ slots,
                                     float* __restrict__ out) {
    int b  = blockIdx.z;
    int n0 = blockIdx.x * 32;
    int c0 = blockIdx.y * 128;
    int x4 = threadIdx.x & 31;        // float4 index within 128-ch half
    int y  = threadIdx.x >> 5;        // 0..7 pixel group

    const float* doutb = dout + (size_t)b * NROWS * C_DIM;
    const int*   slb   = slots + (size_t)b * NROWS;

    __shared__ float t[32][129];

#pragma unroll
    for (int r = 0; r < 4; r++) {
        int px = y + 8 * r;
        int n  = n0 + px;
        size_t row = (size_t)b * HW + n;
        short4 vs = *(const short4*)(qkv + row * QKV_ST + 512 + c0 + x4 * 4);
        float a0 = bf2f(vs.x), a1 = bf2f(vs.y), a2 = bf2f(vs.z), a3 = bf2f(vs.w);
        int cn = cnt[b * HW + n];
        int of = offs[b * HW + n];
        for (int j = 0; j < cn; j++) {
            int dr = slb[of + j];
            float4 d = *(const float4*)(doutb + (size_t)dr * C_DIM + c0 + x4 * 4);
            a0 += d.x; a1 += d.y; a2 += d.z; a3 += d.w;
        }
        t[px][x4 * 4 + 0] = a0;
        t[px][x4 * 4 + 1] = a1;
        t[px][x4 * 4 + 2] = a2;
        t[px][x4 * 4 + 3] = a3;
    }
    __syncthreads();

    {
        int nl = threadIdx.x & 31;            // pixel lane
        int cg = threadIdx.x >> 5;            // 0..7 channel group (16 each)
#pragma unroll
        for (int cc = 0; cc < 16; cc++) {
            int c = c0 + cg * 16 + cc;
            out[((size_t)b * C_DIM + c) * HW + n0 + nl] = t[nl][cg * 16 + cc];
        }
    }
}

// ---------------------------------------------------------------------------
extern "C" void kernel_launch(void* const* d_in, const int* in_sizes, int n_in,
                              void* d_out, int out_size, void* d_ws, size_t ws_size,
                              hipStream_t stream) {
    const float* x    = (const float*)d_in[0];
    const float* aff  = (const float*)d_in[1];
    const float* g    = (const float*)d_in[2];
    const float* beta = (const float*)d_in[3];
    const float* wq   = (const float*)d_in[4];
    const float* wk   = (const float*)d_in[5];
    const float* wv   = (const float*)d_in[6];
    float* out = (float*)d_out;

    char* ws = (char*)d_ws;
    short* qkv  = (short*)ws;                                   ws += (size_t)B_DIM * HW * QKV_ST * 2;
    short* xnT  = (short*)ws;                                   ws += (size_t)B_DIM * HW * C_DIM * 2;
    short* wbuf = (short*)ws;                                   ws += (size_t)QKV_ST * C_DIM * 2;
    float* simsb= (float*)ws;                                   ws += (size_t)B_DIM * S_DIM * T_K * 4;
    int*   idxb = (int*)ws;                                     ws += (size_t)B_DIM * S_DIM * T_K * 4;
    int*   cntb = (int*)ws;                                     ws += (size_t)B_DIM * HW * 4;
    int*   offsb= (int*)ws;                                     ws += (size_t)B_DIM * HW * 4;
    int*   fcnt = (int*)ws;                                     ws += (size_t)B_DIM * HW * 4;
    int*   slots= (int*)ws;                                     ws += (size_t)B_DIM * NROWS * 4;
    float* dout = (float*)ws;

    ln_fused_kernel<<<dim3(HW / 64, B_DIM + 1), 256, 0, stream>>>(
        x, g, beta, xnT, wq, wk, wv, wbuf, cntb, fcnt);
    qkv_mfma_kernel<<<dim3(HW / 128, QKV_ST / 128, B_DIM), 256, 0, stream>>>(
        xnT, wbuf, qkv);
    topk_kernel<<<dim3(S_DIM, B_DIM), 1024, 0, stream>>>(aff, simsb, idxb, cntb);
    scan_kernel<<<dim3(B_DIM), 1024, 0, stream>>>(cntb, offsb);
    fill_kernel<<<dim3(NROWS / 256, B_DIM), 256, 0, stream>>>(idxb, offsb, fcnt, slots);
    attn_kernel<<<dim3(S_DIM, NH, B_DIM), 256, 0, stream>>>(qkv, simsb, idxb, dout);
    transpose_add_kernel<<<dim3(HW / 32, C_DIM / 128, B_DIM), 256, 0, stream>>>(
        qkv, dout, cntb, offsb, slots, out);
}